// Round 1
// 203.799 us; speedup vs baseline: 1.1185x; 1.1185x over previous
//
#include <hip/hip_runtime.h>
#include <math.h>

#define N_NODES 50000
#define N_HEDGE 5000
#define N_EDGES 400000
#define NB 2
#define NC 64
#define NEG 0.2f
#define NROWS (N_NODES * NB)   // 100000

#define SCAT_BLOCKS ((N_EDGES + 255) / 256)   // 1563
#define HEDGE_BLOCKS ((N_HEDGE + 3) / 4)      // 1250

__device__ __forceinline__ unsigned short f2bf(float f) {
    unsigned int u = __float_as_uint(f);
    unsigned int r = (u + 0x7FFFu + ((u >> 16) & 1u)) >> 16;   // RNE
    return (unsigned short)r;
}

// ---------------- GEMM: xw[row][c] bf16, row = n*2+b; epilogue p1/p2
// fused: incidence count (atomics into cnt) + estart binary search
__global__ __launch_bounds__(256, 4) void gemm_kernel(const float* __restrict__ x,
                                                      const float* __restrict__ W,
                                                      const float* __restrict__ att,
                                                      const int* __restrict__ node_idx,
                                                      const int* __restrict__ hedge_idx,
                                                      unsigned short* __restrict__ xwb,
                                                      float* __restrict__ p1,
                                                      float* __restrict__ p2,
                                                      int* __restrict__ cnt,
                                                      int* __restrict__ estart)
{
    __shared__ float xs[64 * 68];
    __shared__ float Ws[64 * 68];
    int t = threadIdx.x;
    int R = blockIdx.x * 64;

    // fused count work (grid 1563*256 = 400128 >= N_EDGES, >= N_HEDGE+1)
    int gid = blockIdx.x * 256 + t;
    if (gid < N_EDGES) atomicAdd(&cnt[node_idx[gid]], 1);
    if (gid <= N_HEDGE) {
        int lo = 0, hi = N_EDGES;
        while (lo < hi) {
            int mid = (lo + hi) >> 1;
            if (hedge_idx[mid] < gid) lo = mid + 1; else hi = mid;
        }
        estart[gid] = lo;
    }

#pragma unroll
    for (int i = 0; i < 4; i++) {
        int lin = t + 256 * i;
        int r = lin >> 4, c4 = lin & 15;
        float4 wv = ((const float4*)W)[lin];
        *(float4*)&Ws[r * 68 + c4 * 4] = wv;
        int g = R + r;
        float4 xv = make_float4(0.f, 0.f, 0.f, 0.f);
        if (g < NROWS) {
            int n = g >> 1, b = g & 1;
            xv = ((const float4*)(x + ((size_t)b * N_NODES + n) * NC))[c4];
        }
        *(float4*)&xs[r * 68 + c4 * 4] = xv;
    }
    __syncthreads();

    int tr = t >> 4, tc = t & 15;
    float acc[4][4];
#pragma unroll
    for (int i = 0; i < 4; i++)
#pragma unroll
        for (int j = 0; j < 4; j++) acc[i][j] = 0.f;

#pragma unroll 4
    for (int k4 = 0; k4 < 16; k4++) {
        float4 xv[4], wv[4];
#pragma unroll
        for (int i = 0; i < 4; i++)
            xv[i] = *(const float4*)&xs[(tr * 4 + i) * 68 + k4 * 4];
#pragma unroll
        for (int kk = 0; kk < 4; kk++)
            wv[kk] = *(const float4*)&Ws[(k4 * 4 + kk) * 68 + tc * 4];
#pragma unroll
        for (int i = 0; i < 4; i++) {
            acc[i][0] = fmaf(xv[i].x, wv[0].x, acc[i][0]);
            acc[i][1] = fmaf(xv[i].x, wv[0].y, acc[i][1]);
            acc[i][2] = fmaf(xv[i].x, wv[0].z, acc[i][2]);
            acc[i][3] = fmaf(xv[i].x, wv[0].w, acc[i][3]);
            acc[i][0] = fmaf(xv[i].y, wv[1].x, acc[i][0]);
            acc[i][1] = fmaf(xv[i].y, wv[1].y, acc[i][1]);
            acc[i][2] = fmaf(xv[i].y, wv[1].z, acc[i][2]);
            acc[i][3] = fmaf(xv[i].y, wv[1].w, acc[i][3]);
            acc[i][0] = fmaf(xv[i].z, wv[2].x, acc[i][0]);
            acc[i][1] = fmaf(xv[i].z, wv[2].y, acc[i][1]);
            acc[i][2] = fmaf(xv[i].z, wv[2].z, acc[i][2]);
            acc[i][3] = fmaf(xv[i].z, wv[2].w, acc[i][3]);
            acc[i][0] = fmaf(xv[i].w, wv[3].x, acc[i][0]);
            acc[i][1] = fmaf(xv[i].w, wv[3].y, acc[i][1]);
            acc[i][2] = fmaf(xv[i].w, wv[3].z, acc[i][2]);
            acc[i][3] = fmaf(xv[i].w, wv[3].w, acc[i][3]);
        }
    }

    float a1x = att[tc * 4], a1y = att[tc * 4 + 1], a1z = att[tc * 4 + 2], a1w = att[tc * 4 + 3];
    float a2x = att[64 + tc * 4], a2y = att[64 + tc * 4 + 1], a2z = att[64 + tc * 4 + 2], a2w = att[64 + tc * 4 + 3];
#pragma unroll
    for (int i = 0; i < 4; i++) {
        int g = R + tr * 4 + i;
        if (g < NROWS) {
            ushort4 bv;
            bv.x = f2bf(acc[i][0]); bv.y = f2bf(acc[i][1]);
            bv.z = f2bf(acc[i][2]); bv.w = f2bf(acc[i][3]);
            ((ushort4*)(xwb + (size_t)g * 64))[tc] = bv;
        }
        float v1 = acc[i][0] * a1x + acc[i][1] * a1y + acc[i][2] * a1z + acc[i][3] * a1w;
        float v2 = acc[i][0] * a2x + acc[i][1] * a2y + acc[i][2] * a2z + acc[i][3] * a2w;
#pragma unroll
        for (int off = 8; off >= 1; off >>= 1) {
            v1 += __shfl_xor(v1, off, 64);
            v2 += __shfl_xor(v2, off, 64);
        }
        if (tc == 0 && g < NROWS) { p1[g] = v1; p2[g] = v2; }
    }
}

// ---------------- segment-base allocator: block-local scan + one atomicAdd per block
// Segment bases need only be disjoint+contiguous, not in node order, so a single
// order-free atomic allocation replaces the 3-kernel prefix scan.
__global__ __launch_bounds__(256) void alloc_kernel(const int* __restrict__ cnt,
                                                    int* __restrict__ base,
                                                    int* __restrict__ gcursor)
{
    __shared__ int sm[256];
    __shared__ int bbase;
    int tid = threadIdx.x;
    int i = blockIdx.x * 256 + tid;
    int v = (i < N_NODES) ? cnt[i] : 0;
    sm[tid] = v;
    __syncthreads();
    for (int off = 1; off < 256; off <<= 1) {
        int t = (tid >= off) ? sm[tid - off] : 0;
        __syncthreads();
        sm[tid] += t;
        __syncthreads();
    }
    if (tid == 255) bbase = atomicAdd(gcursor, sm[255]);
    __syncthreads();
    if (i < N_NODES) base[i] = bbase + sm[tid] - v;
}

// ---------------- fused: scatter (CSR perm) + per-hyperedge p2 sum (same dep level)
__global__ __launch_bounds__(256) void sh_kernel(const int* __restrict__ node_idx,
                                                 const int* __restrict__ hedge_idx,
                                                 const int* __restrict__ base,
                                                 int* __restrict__ cursor,
                                                 int* __restrict__ hperm,
                                                 int* __restrict__ pos,
                                                 const float* __restrict__ p2,
                                                 const int* __restrict__ estart,
                                                 float* __restrict__ s2)
{
    int blk = blockIdx.x;
    if (blk < SCAT_BLOCKS) {
        int e = blk * 256 + threadIdx.x;
        if (e >= N_EDGES) return;
        int n = node_idx[e];
        int p = base[n] + atomicAdd(&cursor[n], 1);
        hperm[p] = hedge_idx[e];
        pos[e] = p;
    } else {
        int wv = (blk - SCAT_BLOCKS) * 4 + (threadIdx.x >> 6);
        if (wv >= N_HEDGE) return;
        int lane = threadIdx.x & 63;
        int s = estart[wv], e1 = estart[wv + 1];
        float a0 = 0.f, a1 = 0.f;
        for (int e = s + lane; e < e1; e += 64) {
            int n = node_idx[e];
            float2 p = ((const float2*)p2)[n];
            a0 += p.x; a1 += p.y;
        }
#pragma unroll
        for (int off = 32; off >= 1; off >>= 1) {
            a0 += __shfl_xor(a0, off, 64);
            a1 += __shfl_xor(a1, off, 64);
        }
        if (lane == 0) {
            s2[wv * 2] = a0;
            s2[wv * 2 + 1] = a1;
        }
    }
}

// ---------------- fused logits + leaky relu + per-node softmax (CSR order, in place)
__global__ void softmax_kernel(const int* __restrict__ base,
                               const int* __restrict__ cnt,
                               const int* __restrict__ hperm,
                               const float* __restrict__ p1,
                               const float* __restrict__ s2,
                               float* __restrict__ acsr)
{
    int n = blockIdx.x * blockDim.x + threadIdx.x;
    if (n >= N_NODES) return;
    int s = base[n];
    int e1 = s + cnt[n];
    if (s == e1) return;
    float pn0 = p1[n * 2], pn1 = p1[n * 2 + 1];
    float2* a = (float2*)acsr;
    const float2* s2v = (const float2*)s2;
    float mx0 = -INFINITY, mx1 = -INFINITY;
    for (int j = s; j < e1; j++) {
        int h = hperm[j];
        float2 sv = s2v[h];
        float r0 = pn0 + sv.x; r0 = (r0 >= 0.f) ? r0 : NEG * r0;
        float r1 = pn1 + sv.y; r1 = (r1 >= 0.f) ? r1 : NEG * r1;
        a[j] = make_float2(r0, r1);
        mx0 = fmaxf(mx0, r0); mx1 = fmaxf(mx1, r1);
    }
    float s0 = 0.f, s1 = 0.f;
    for (int j = s; j < e1; j++) {
        float2 v = a[j];
        float e0 = expf(v.x - mx0), e1f = expf(v.y - mx1);
        a[j] = make_float2(e0, e1f);
        s0 += e0; s1 += e1f;
    }
    float i0 = 1.0f / s0, i1 = 1.0f / s1;
    for (int j = s; j < e1; j++) {
        float2 v = a[j];
        a[j] = make_float2(v.x * i0, v.y * i1);
    }
}

// ---------------- pass 1: m[h][k] = (1/deg) * sum_{e in h} alpha[e,b(k)]*xw[node[e]][k]
__global__ __launch_bounds__(128) void m_kernel(const unsigned short* __restrict__ xwb,
                                                const int* __restrict__ node_idx,
                                                const int* __restrict__ estart,
                                                const int* __restrict__ pos,
                                                const float* __restrict__ acsr,
                                                float* __restrict__ m)
{
    __shared__ float red[128];
    int h = blockIdx.x;
    int t = threadIdx.x;
    int w = t >> 6, l = t & 63;
    int b = l >> 5;                       // channel 2l: b = (2l)>>6
    int s = estart[h], e1 = estart[h + 1];
    float ax = 0.f, ay = 0.f;
    int e = s + w;
    for (; e + 6 < e1; e += 8) {
        int n0 = node_idx[e],     n1 = node_idx[e + 2];
        int n2 = node_idx[e + 4], n3 = node_idx[e + 6];
        int q0 = pos[e],     q1 = pos[e + 2];
        int q2 = pos[e + 4], q3 = pos[e + 6];
        float a0 = acsr[q0 * 2 + b], a1 = acsr[q1 * 2 + b];
        float a2 = acsr[q2 * 2 + b], a3 = acsr[q3 * 2 + b];
        unsigned int u0 = *(const unsigned int*)&xwb[(size_t)n0 * 128 + 2 * l];
        unsigned int u1 = *(const unsigned int*)&xwb[(size_t)n1 * 128 + 2 * l];
        unsigned int u2 = *(const unsigned int*)&xwb[(size_t)n2 * 128 + 2 * l];
        unsigned int u3 = *(const unsigned int*)&xwb[(size_t)n3 * 128 + 2 * l];
        ax = fmaf(a0, __uint_as_float(u0 << 16), ax);
        ay = fmaf(a0, __uint_as_float(u0 & 0xffff0000u), ay);
        ax = fmaf(a1, __uint_as_float(u1 << 16), ax);
        ay = fmaf(a1, __uint_as_float(u1 & 0xffff0000u), ay);
        ax = fmaf(a2, __uint_as_float(u2 << 16), ax);
        ay = fmaf(a2, __uint_as_float(u2 & 0xffff0000u), ay);
        ax = fmaf(a3, __uint_as_float(u3 << 16), ax);
        ay = fmaf(a3, __uint_as_float(u3 & 0xffff0000u), ay);
    }
    for (; e < e1; e += 2) {
        int n = node_idx[e];
        float a0 = acsr[pos[e] * 2 + b];
        unsigned int u = *(const unsigned int*)&xwb[(size_t)n * 128 + 2 * l];
        ax = fmaf(a0, __uint_as_float(u << 16), ax);
        ay = fmaf(a0, __uint_as_float(u & 0xffff0000u), ay);
    }
    if (w == 1) { red[2 * l] = ax; red[2 * l + 1] = ay; }
    __syncthreads();
    if (w == 0) {
        ax += red[2 * l]; ay += red[2 * l + 1];
        int d = e1 - s;
        float binv = (d > 0) ? 1.0f / (float)d : 0.0f;
        ((float2*)(m + (size_t)h * 128))[l] = make_float2(binv * ax, binv * ay);
    }
}

// ---------------- pass 2: out[b][n][c] = deg[n] * sum_j alpha_csr[j,b]*m[hperm[j]][k]
// 1 wave per node (avg degree ~8): no LDS, no barrier, 4 nodes per 256-block.
__global__ __launch_bounds__(256) void out_kernel(const float* __restrict__ m,
                                                  const int* __restrict__ hperm,
                                                  const int* __restrict__ base,
                                                  const int* __restrict__ cnt,
                                                  const float* __restrict__ acsr,
                                                  float* __restrict__ out)
{
    int n = blockIdx.x * 4 + (threadIdx.x >> 6);
    if (n >= N_NODES) return;
    int l = threadIdx.x & 63;
    int b = l >> 5;
    int s = base[n];
    int d = cnt[n];
    int e1 = s + d;
    float ax = 0.f, ay = 0.f;
    int j = s;
    for (; j + 3 < e1; j += 4) {
        int h0 = hperm[j],     h1 = hperm[j + 1];
        int h2 = hperm[j + 2], h3 = hperm[j + 3];
        float a0 = acsr[j * 2 + b],       a1 = acsr[(j + 1) * 2 + b];
        float a2 = acsr[(j + 2) * 2 + b], a3 = acsr[(j + 3) * 2 + b];
        float2 v0 = ((const float2*)(m + (size_t)h0 * 128))[l];
        float2 v1 = ((const float2*)(m + (size_t)h1 * 128))[l];
        float2 v2 = ((const float2*)(m + (size_t)h2 * 128))[l];
        float2 v3 = ((const float2*)(m + (size_t)h3 * 128))[l];
        ax = fmaf(a0, v0.x, ax); ay = fmaf(a0, v0.y, ay);
        ax = fmaf(a1, v1.x, ax); ay = fmaf(a1, v1.y, ay);
        ax = fmaf(a2, v2.x, ax); ay = fmaf(a2, v2.y, ay);
        ax = fmaf(a3, v3.x, ax); ay = fmaf(a3, v3.y, ay);
    }
    for (; j < e1; j++) {
        int h = hperm[j];
        float a0 = acsr[j * 2 + b];
        float2 v = ((const float2*)(m + (size_t)h * 128))[l];
        ax = fmaf(a0, v.x, ax); ay = fmaf(a0, v.y, ay);
    }
    float deg = (float)d;
    int c = (2 * l) & 63;
    float2 val = make_float2(deg * ax, deg * ay);
    float* dst = out + (size_t)b * N_NODES * 64 + (size_t)n * 64 + c;
    __builtin_nontemporal_store(val.x, &dst[0]);
    __builtin_nontemporal_store(val.y, &dst[1]);
}

extern "C" void kernel_launch(void* const* d_in, const int* in_sizes, int n_in,
                              void* d_out, int out_size, void* d_ws, size_t ws_size,
                              hipStream_t stream)
{
    const float* x      = (const float*)d_in[0];
    const float* W      = (const float*)d_in[1];
    const float* att    = (const float*)d_in[2];
    const int* node_idx = (const int*)d_in[3];
    const int* hedge_idx= (const int*)d_in[4];
    float* out = (float*)d_out;

    // workspace layout — ~23.2MB total
    unsigned short* xwb = (unsigned short*)d_ws;        // 6,400,000 ushort (12.8MB)
    float* p1     = (float*)(xwb + (size_t)NROWS * NC); // 100,000
    float* p2     = p1 + NROWS;                         // 100,000
    float* s2     = p2 + NROWS;                         // 10,000
    float* acsr   = s2 + 10000;                         // 800,000
    float* m      = acsr + 2 * N_EDGES;                 // 640,000
    int* estart  = (int*)(m + (size_t)N_HEDGE * NB * NC); // 5,008 (padded)
    int* cnt     = estart + 5008;                       // 50,000  ┐ contiguous
    int* cursor  = cnt + N_NODES;                       // 50,000  │ memset
    int* gcursor = cursor + N_NODES;                    // 8       ┘ region
    int* base    = gcursor + 8;                         // 50,000
    int* hperm   = base + N_NODES;                      // 400,000
    int* pos     = hperm + N_EDGES;                     // 400,000

    hipMemsetAsync(cnt, 0, (size_t)(2 * N_NODES + 8) * sizeof(int), stream);

    gemm_kernel<<<(NROWS + 63) / 64, 256, 0, stream>>>(x, W, att, node_idx, hedge_idx,
                                                       xwb, p1, p2, cnt, estart);
    alloc_kernel<<<(N_NODES + 255) / 256, 256, 0, stream>>>(cnt, base, gcursor);
    sh_kernel<<<SCAT_BLOCKS + HEDGE_BLOCKS, 256, 0, stream>>>(node_idx, hedge_idx, base,
                                                              cursor, hperm, pos,
                                                              p2, estart, s2);
    softmax_kernel<<<(N_NODES + 255) / 256, 256, 0, stream>>>(base, cnt, hperm, p1, s2, acsr);
    m_kernel<<<N_HEDGE, 128, 0, stream>>>(xwb, node_idx, estart, pos, acsr, m);
    out_kernel<<<(N_NODES + 3) / 4, 256, 0, stream>>>(m, hperm, base, cnt, acsr, out);
}